// Round 11
// baseline (393.960 us; speedup 1.0000x reference)
//
#include <hip/hip_runtime.h>
#include <cstdint>
#include <cstddef>

#define HH 96
#define WW 96
#define NN 8
#define CIN 512
#define CMID 256
#define CO2 576

typedef __attribute__((ext_vector_type(4))) float f32x4;
typedef __attribute__((ext_vector_type(8))) short short8;

static __device__ __forceinline__ unsigned short f2bf(float f) {
    unsigned int u = __float_as_uint(f);
    u += 0x7fffu + ((u >> 16) & 1u);
    return (unsigned short)(u >> 16);
}

static __device__ __forceinline__ void gl_lds16(const void* g, void* l) {
    __builtin_amdgcn_global_load_lds(
        (const __attribute__((address_space(1))) unsigned int*)g,
        (__attribute__((address_space(3))) unsigned int*)l, 16, 0, 0);
}

// w1 (256,512,3,3) OIHW fp32 -> w1p: 144 slabs [(cc,tap)] of 8192 shorts.
// w2 -> w2p [kc(8)][tc(36)][lane(64)][e(8)]; zr = 2KB zero region.
__global__ __launch_bounds__(256) void prep_w_kernel(
    const float* __restrict__ w1, const float* __restrict__ w2,
    unsigned short* __restrict__ w1p, unsigned short* __restrict__ w2p,
    float* __restrict__ zr)
{
    size_t i = (size_t)blockIdx.x * 256 + threadIdx.x;
    if (blockIdx.x == 0 && threadIdx.x < 128) {
        float4 z; z.x = 0.f; z.y = 0.f; z.z = 0.f; z.w = 0.f;
        reinterpret_cast<float4*>(zr)[threadIdx.x] = z;
    }
    if (i < (size_t)144 * 8192) {
        int sb = (int)(i >> 13);
        int r13 = (int)(i & 8191);
        int co16 = r13 >> 9;
        int g = (r13 >> 7) & 3;
        int sl = (r13 >> 3) & 15;
        int e = (int)(i & 7);
        int cc = sb / 9, tap = sb % 9;
        int co = co16 * 16 + sl;
        int ci = cc * 32 + g * 8 + e;
        w1p[i] = f2bf(w1[((size_t)co * CIN + ci) * 9 + tap]);
    }
    if (i < (size_t)8 * 36 * 64 * 8) {
        int idx = (int)i;
        int e = idx & 7;
        int ln = (idx >> 3) & 63;
        int tc = (idx >> 9) % 36;
        int kc = (idx >> 9) / 36;
        int sl = ln & 15, g = ln >> 4;
        int co = tc * 16 + sl;
        int ci = kc * 32 + g * 8 + e;
        w2p[idx] = f2bf(w2[(size_t)co * CMID + ci]);
    }
}

// transpose v2: feature (N,512,96,96) fp32 -> featT [N][H][W][512] bf16.
// Loads scalar-coalesced into 65-pad LDS; stores packed 16B/lane.
__global__ __launch_bounds__(256) void transpose_kernel(
    const float* __restrict__ f, unsigned short* __restrict__ ft)
{
    __shared__ float t[96 * 65];
    const int tid = threadIdx.x;
    const int b = blockIdx.x;
    const int n = b / HH, h = b % HH;
    for (int cb = 0; cb < 8; ++cb) {
        __syncthreads();
        #pragma unroll
        for (int it = 0; it < 24; ++it) {
            int idx = tid + it * 256;          // 0..6143
            int cl = idx / 96, w = idx - cl * 96;
            t[w * 65 + cl] = f[(((size_t)n * CIN + cb * 64 + cl) * HH + h) * WW + w];
        }
        __syncthreads();
        #pragma unroll
        for (int it = 0; it < 3; ++it) {
            int idx = tid + it * 256;          // 0..767 = (w, c8)
            int c8 = idx & 7, w = idx >> 3;
            const float* tp = &t[w * 65 + c8 * 8];
            ushort4 lo4, hi4;
            lo4.x = f2bf(tp[0]); lo4.y = f2bf(tp[1]);
            lo4.z = f2bf(tp[2]); lo4.w = f2bf(tp[3]);
            hi4.x = f2bf(tp[4]); hi4.y = f2bf(tp[5]);
            hi4.z = f2bf(tp[6]); hi4.w = f2bf(tp[7]);
            unsigned short* op =
                &ft[(((size_t)n * HH + h) * WW + w) * CIN + cb * 64 + c8 * 8];
            *reinterpret_cast<ushort4*>(op) = lo4;
            *reinterpret_cast<ushort4*>(op + 4) = hi4;
        }
    }
}

// conv1 v6 (r8/r10-proven): 3x3, 512->256, bias+ReLU. One block per (n,h),
// 512 thr = 8 waves, wave = 32-co group, tile 96x32 (acc[6][2]).
// B: global_load_lds DMA at chunk start, pre-swizzled per-lane src.
// A: registers from fragment-ordered w1p, depth-1 dbuf w/ compile-time parity.
__global__ __launch_bounds__(512, 4) void conv1_kernel(
    const unsigned short* __restrict__ featT,
    const unsigned short* __restrict__ w1p,
    const float* __restrict__ b1,
    const unsigned short* __restrict__ zr,
    unsigned short* __restrict__ x)
{
    __shared__ unsigned short fsB[2][9728];   // 2 x 19456 B (1216 slots x 16B)
    const int tid = threadIdx.x;
    int bid = blockIdx.x;
    bid = (bid & 7) * 96 + (bid >> 3);        // XCD swizzle (768 = 8*96)
    const int n = bid / HH, h = bid % HH;
    const int wave = tid >> 6, lane = tid & 63;
    const int g = lane >> 4, sl = lane & 15;

    f32x4 acc[6][2];
    #pragma unroll
    for (int i = 0; i < 6; ++i) {
        acc[i][0] = (f32x4)0.0f;
        acc[i][1] = (f32x4)0.0f;
    }

    const unsigned short* gp[3];
    #pragma unroll
    for (int j = 0; j < 3; ++j) {
        int q = j * 8 + wave;
        int slot = q * 64 + lane;
        int cslot = slot >> 2, sx = slot & 3;
        int rr = cslot / 98, lw = cslot - rr * 98;
        int s = sx ^ ((lw >> 1) & 3);
        int row = h - 1 + rr;
        bool ok = (rr < 3) && (lw >= 1) && (lw <= 96) && ((unsigned)row < HH);
        gp[j] = ok ? &featT[(((size_t)n * HH + row) * WW + (lw - 1)) * CIN + s * 8]
                   : zr;
    }
    const int nq = (wave < 3) ? 3 : 2;

    short8 af0[2], af1[2];

    #pragma unroll
    for (int j = 0; j < 3; ++j) {
        if (j < nq) {
            int q = j * 8 + wave;
            gl_lds16(gp[j], &fsB[0][q * 512]);
        }
        gp[j] += 32;
    }
    #pragma unroll
    for (int tc = 0; tc < 2; ++tc)
        af0[tc] = *reinterpret_cast<const short8*>(
            &w1p[(size_t)(((wave * 2 + tc) * 64 + lane) * 8)]);
    __syncthreads();

    auto afload = [&](short8 (&af)[2], int sb1) {
        const unsigned short* ap = &w1p[(size_t)sb1 * 8192];
        #pragma unroll
        for (int tc = 0; tc < 2; ++tc)
            af[tc] = *reinterpret_cast<const short8*>(
                &ap[((wave * 2 + tc) * 64 + lane) * 8]);
    };
    auto compute = [&](short8 (&af)[2], int par, int ki, int kj) {
        #pragma unroll
        for (int ts = 0; ts < 6; ++ts) {
            int lw = ts * 16 + sl + kj;
            int sx = g ^ ((lw >> 1) & 3);
            short8 bf = *reinterpret_cast<const short8*>(
                &fsB[par][((ki * 98 + lw) * 4 + sx) * 8]);
            acc[ts][0] = __builtin_amdgcn_mfma_f32_16x16x32_bf16(
                af[0], bf, acc[ts][0], 0, 0, 0);
            acc[ts][1] = __builtin_amdgcn_mfma_f32_16x16x32_bf16(
                af[1], bf, acc[ts][1], 0, 0, 0);
        }
    };

    for (int ccp = 0; ccp < 8; ++ccp) {
        #pragma unroll
        for (int par = 0; par < 2; ++par) {
            const int cc = ccp * 2 + par;
            if (cc < 15) {
                #pragma unroll
                for (int j = 0; j < 3; ++j) {
                    if (j < nq) {
                        int q = j * 8 + wave;
                        gl_lds16(gp[j], &fsB[par ^ 1][q * 512]);
                    }
                    gp[j] += 32;
                }
            }
            #pragma unroll
            for (int tap = 0; tap < 9; ++tap) {
                const int sbr = cc * 9 + tap;
                const int ki = tap / 3, kj = tap % 3;
                if (((par + tap) & 1) == 0) {
                    if (sbr < 143) afload(af1, sbr + 1);
                    compute(af0, par, ki, kj);
                } else {
                    if (sbr < 143) afload(af0, sbr + 1);
                    compute(af1, par, ki, kj);
                }
            }
            if (cc < 15) __syncthreads();
        }
    }

    const size_t rowbase = ((size_t)n * HH + h);
    #pragma unroll
    for (int ts = 0; ts < 6; ++ts) {
        int sp = ts * 16 + sl;
        unsigned short* xp = &x[(rowbase * WW + sp) * CMID];
        #pragma unroll
        for (int tc = 0; tc < 2; ++tc) {
            int co0 = wave * 32 + tc * 16 + g * 4;
            const float4 bb = *reinterpret_cast<const float4*>(&b1[co0]);
            float v0 = acc[ts][tc][0] + bb.x;
            float v1 = acc[ts][tc][1] + bb.y;
            float v2 = acc[ts][tc][2] + bb.z;
            float v3 = acc[ts][tc][3] + bb.w;
            v0 = v0 > 0.f ? v0 : 0.f;
            v1 = v1 > 0.f ? v1 : 0.f;
            v2 = v2 > 0.f ? v2 : 0.f;
            v3 = v3 > 0.f ? v3 : 0.f;
            ushort4 st;
            st.x = f2bf(v0); st.y = f2bf(v1); st.z = f2bf(v2); st.w = f2bf(v3);
            *reinterpret_cast<ushort4*>(&xp[co0]) = st;
        }
    }
}

// conv2 v10 (1x1, 256->576) + bias*0.25 + softmax + flow assembly.
// SAME structure as v9; ONLY change: __launch_bounds__(256) with NO min-wave
// arg — the (256,3) occupancy target made the allocator pick a sub-demand
// VGPR budget and spill accumulators to scratch (the r2/r7 pathology).
// Unconstrained, the allocator takes ~155 regs (3 waves/SIMD by VGPR anyway).
__global__ __launch_bounds__(256) void conv2_kernel(
    const unsigned short* __restrict__ x,
    const unsigned short* __restrict__ w2p,
    const float* __restrict__ b2,
    const float* __restrict__ flow,
    float* __restrict__ out)
{
    __shared__ float lo[16 * 384];               // 24576 B
    const int tid = threadIdx.x;
    int bid = blockIdx.x;
    bid = (bid & 7) * 192 + (bid >> 3);          // XCD swizzle (1536 = 8*192)
    const int n = bid / 192;
    const int rem = bid % 192;
    const int h = rem >> 1, half = rem & 1;
    const int q = tid >> 6, lane = tid & 63;
    const int g = lane >> 4, sl = lane & 15;
    const int p0 = half * 48;

    f32x4 acc[9][3];
    #pragma unroll
    for (int k = 0; k < 9; ++k)
        #pragma unroll
        for (int u = 0; u < 3; ++u) acc[k][u] = (f32x4)0.0f;

    const unsigned short* xp = &x[(((size_t)n * HH + h) * WW + p0) * CMID];
    #pragma unroll
    for (int kc = 0; kc < 8; ++kc) {
        short8 bf[3];
        #pragma unroll
        for (int u = 0; u < 3; ++u)
            bf[u] = *reinterpret_cast<const short8*>(
                &xp[(u * 16 + sl) * CMID + kc * 32 + g * 8]);
        const unsigned short* wkc = &w2p[(size_t)kc * 36 * 512];
        #pragma unroll
        for (int k = 0; k < 9; ++k) {
            int tc = 4 * k + q;
            short8 af = *reinterpret_cast<const short8*>(&wkc[(tc * 64 + lane) * 8]);
            #pragma unroll
            for (int u = 0; u < 3; ++u)
                acc[k][u] = __builtin_amdgcn_mfma_f32_16x16x32_bf16(
                    af, bf[u], acc[k][u], 0, 0, 0);
        }
    }

    #pragma unroll
    for (int k = 0; k < 9; ++k) {
        int co0 = (4 * k + q) * 16 + g * 4;
        const float4 bb = *reinterpret_cast<const float4*>(&b2[co0]);
        #pragma unroll
        for (int u = 0; u < 3; ++u) {
            acc[k][u][0] = 0.25f * (acc[k][u][0] + bb.x);
            acc[k][u][1] = 0.25f * (acc[k][u][1] + bb.y);
            acc[k][u][2] = 0.25f * (acc[k][u][2] + bb.z);
            acc[k][u][3] = 0.25f * (acc[k][u][3] + bb.w);
        }
    }

    #pragma unroll
    for (int u = 0; u < 3; ++u) {
        const int s_abs = p0 + u * 16 + sl;
        float pf[2][9];
        #pragma unroll
        for (int ch = 0; ch < 2; ++ch) {
            #pragma unroll
            for (int ki = 0; ki < 3; ++ki) {
                #pragma unroll
                for (int kj = 0; kj < 3; ++kj) {
                    int hh2 = h + ki - 1, ww2 = s_abs + kj - 1;
                    float v = 0.f;
                    if ((unsigned)hh2 < HH && (unsigned)ww2 < WW)
                        v = flow[(((size_t)n * 2 + ch) * HH + hh2) * WW + ww2];
                    pf[ch][ki * 3 + kj] = 8.f * v;
                }
            }
        }
        #pragma unroll
        for (int i = 0; i < 4; ++i) {
            int pp = 16 * q + 4 * g + i;
            float L[9];
            #pragma unroll
            for (int k = 0; k < 9; ++k) L[k] = acc[k][u][i];
            float mx = L[0];
            #pragma unroll
            for (int k = 1; k < 9; ++k) mx = fmaxf(mx, L[k]);
            float e[9], sum = 0.f;
            #pragma unroll
            for (int k = 0; k < 9; ++k) { e[k] = __expf(L[k] - mx); sum += e[k]; }
            float inv = 1.f / sum;
            int py = pp >> 3, px = pp & 7;
            #pragma unroll
            for (int ch = 0; ch < 2; ++ch) {
                float o = 0.f;
                #pragma unroll
                for (int k = 0; k < 9; ++k) o += e[k] * pf[ch][k];
                lo[(ch * 8 + py) * 384 + (u * 16 + sl) * 8 + px] = o * inv;
            }
        }
    }
    __syncthreads();

    #pragma unroll
    for (int it = 0; it < 6; ++it) {
        int idx = tid + it * 256;                 // float4 index, 0..1535
        int row = idx / 96, c4 = idx - row * 96;
        int ch = row >> 3, py = row & 7;
        float4 v = *reinterpret_cast<const float4*>(&lo[row * 384 + c4 * 4]);
        *reinterpret_cast<float4*>(
            &out[(((size_t)n * 2 + ch) * 768 + h * 8 + py) * 768 +
                 half * 384 + c4 * 4]) = v;
    }
}

extern "C" void kernel_launch(void* const* d_in, const int* in_sizes, int n_in,
                              void* d_out, int out_size, void* d_ws, size_t ws_size,
                              hipStream_t stream)
{
    const float* feature = (const float*)d_in[0];
    const float* flow    = (const float*)d_in[1];
    const float* w1      = (const float*)d_in[2];
    const float* b1      = (const float*)d_in[3];
    const float* w2      = (const float*)d_in[4];
    const float* b2      = (const float*)d_in[5];
    float* out = (float*)d_out;

    const size_t featT_bytes = (size_t)NN * HH * WW * CIN * 2;
    const size_t x_bytes     = (size_t)NN * HH * WW * CMID * 2;
    const size_t w1p_bytes   = (size_t)144 * 8192 * 2;
    const size_t w2p_bytes   = (size_t)CO2 * CMID * 2;
    const size_t zr_bytes    = 2048;
    if (ws_size < featT_bytes + x_bytes + w1p_bytes + w2p_bytes + zr_bytes) return;

    char* ws = (char*)d_ws;
    unsigned short* featT = (unsigned short*)ws;
    unsigned short* xbuf  = (unsigned short*)(ws + featT_bytes);
    unsigned short* w1p   = (unsigned short*)(ws + featT_bytes + x_bytes);
    unsigned short* w2p   = (unsigned short*)(ws + featT_bytes + x_bytes + w1p_bytes);
    unsigned short* zr    = (unsigned short*)(ws + featT_bytes + x_bytes + w1p_bytes + w2p_bytes);

    prep_w_kernel<<<4608, 256, 0, stream>>>(w1, w2, w1p, w2p, (float*)zr);
    transpose_kernel<<<NN * HH, 256, 0, stream>>>(feature, featT);
    conv1_kernel<<<NN * HH, 512, 0, stream>>>(featT, w1p, b1, zr, xbuf);
    conv2_kernel<<<NN * HH * 2, 256, 0, stream>>>(xbuf, w2p, b2, flow, out);
}

// Round 12
// 280.504 us; speedup vs baseline: 1.4045x; 1.4045x over previous
//
#include <hip/hip_runtime.h>
#include <cstdint>
#include <cstddef>

#define HH 96
#define WW 96
#define NN 8
#define CIN 512
#define CMID 256
#define CO2 576

typedef __attribute__((ext_vector_type(4))) float f32x4;
typedef __attribute__((ext_vector_type(8))) short short8;

static __device__ __forceinline__ unsigned short f2bf(float f) {
    unsigned int u = __float_as_uint(f);
    u += 0x7fffu + ((u >> 16) & 1u);
    return (unsigned short)(u >> 16);
}

// w1 (256,512,3,3) OIHW fp32 -> w1p: 144 slabs [(cc,tap)] of 8192 shorts.
// w2 -> w2p [kc(8)][tc(36)][lane(64)][e(8)].
__global__ __launch_bounds__(256) void prep_w_kernel(
    const float* __restrict__ w1, const float* __restrict__ w2,
    unsigned short* __restrict__ w1p, unsigned short* __restrict__ w2p)
{
    size_t i = (size_t)blockIdx.x * 256 + threadIdx.x;
    if (i < (size_t)144 * 8192) {
        int sb = (int)(i >> 13);
        int r13 = (int)(i & 8191);
        int co16 = r13 >> 9;
        int g = (r13 >> 7) & 3;
        int sl = (r13 >> 3) & 15;
        int e = (int)(i & 7);
        int cc = sb / 9, tap = sb % 9;
        int co = co16 * 16 + sl;
        int ci = cc * 32 + g * 8 + e;
        w1p[i] = f2bf(w1[((size_t)co * CIN + ci) * 9 + tap]);
    }
    if (i < (size_t)8 * 36 * 64 * 8) {
        int idx = (int)i;
        int e = idx & 7;
        int ln = (idx >> 3) & 63;
        int tc = (idx >> 9) % 36;
        int kc = (idx >> 9) / 36;
        int sl = ln & 15, g = ln >> 4;
        int co = tc * 16 + sl;
        int ci = kc * 32 + g * 8 + e;
        w2p[idx] = f2bf(w2[(size_t)co * CMID + ci]);
    }
}

// conv1 v8 (fused transpose): 3x3, 512->256, bias+ReLU, reads NCHW feature
// DIRECTLY. One block per (n,h), 512 thr = 8 waves, wave = 32-co group,
// tile 96x32 (acc[6][2]).
// B: reg-staged fp32 loads (lane-consecutive w = coalesced), issue-early /
//    cvt+write-late into the PROVEN swizzled LDS layout
//    (chunk c = (rr*98+lw)*4 + (s ^ ((lw>>1)&3)); pads written as zeros).
// A: registers from fragment-ordered w1p, depth-1 dbuf w/ compile-time parity.
__global__ __launch_bounds__(512, 4) void conv1_kernel(
    const float* __restrict__ feature,
    const unsigned short* __restrict__ w1p,
    const float* __restrict__ b1,
    unsigned short* __restrict__ x)
{
    __shared__ unsigned short fsB[2][9408];   // 2 x 18816 B (1176 slots x 16B)
    const int tid = threadIdx.x;
    int bid = blockIdx.x;
    bid = (bid & 7) * 96 + (bid >> 3);        // XCD swizzle (768 = 8*96)
    const int n = bid / HH, h = bid % HH;
    const int wave = tid >> 6, lane = tid & 63;
    const int g = lane >> 4, sl = lane & 15;

    f32x4 acc[6][2];
    #pragma unroll
    for (int i = 0; i < 6; ++i) {
        acc[i][0] = (f32x4)0.0f;
        acc[i][1] = (f32x4)0.0f;
    }

    // staging map: 1176 slots = seg(12 = rr*4+s) x lw(98). thread t owns
    // slots t, t+512, t+1024 (act only if < 1176). Pad slots (lw 0/97, OOB
    // row) are written as zeros each chunk (halo zero-pad).
    bool act[3], vld[3];
    int gbase[3], soff[3];
    #pragma unroll
    for (int k = 0; k < 3; ++k) {
        int slot = tid + k * 512;
        act[k] = (slot < 1176);
        int ss = act[k] ? slot : 0;
        int seg = ss / 98, lw = ss - seg * 98;
        int rr = seg >> 2, s = seg & 3;
        int row = h - 1 + rr;
        int w = lw - 1;
        vld[k] = act[k] && (lw >= 1) && (lw <= 96) && ((unsigned)row < HH);
        int rs = vld[k] ? row : 0;
        int wsf = vld[k] ? w : 0;
        gbase[k] = ((n * CIN + s * 8) * HH + rs) * WW + wsf;
        soff[k] = ((rr * 98 + lw) * 4 + (s ^ ((lw >> 1) & 3))) * 8;
    }

    float stg[3][8];
    auto loadStg = [&](int cc) {
        const int cofs = cc * 32 * (HH * WW);
        #pragma unroll
        for (int k = 0; k < 3; ++k) {
            #pragma unroll
            for (int e = 0; e < 8; ++e)
                stg[k][e] = vld[k] ? feature[gbase[k] + cofs + e * (HH * WW)]
                                   : 0.f;
        }
    };
    auto writeStg = [&](int buf) {
        #pragma unroll
        for (int k = 0; k < 3; ++k) {
            if (act[k]) {
                short8 v;
                #pragma unroll
                for (int e = 0; e < 8; ++e) v[e] = (short)f2bf(stg[k][e]);
                *reinterpret_cast<short8*>(&fsB[buf][soff[k]]) = v;
            }
        }
    };

    short8 af0[2], af1[2];
    auto afload = [&](short8 (&af)[2], int sb1) {
        const unsigned short* ap = &w1p[(size_t)sb1 * 8192];
        #pragma unroll
        for (int tc = 0; tc < 2; ++tc)
            af[tc] = *reinterpret_cast<const short8*>(
                &ap[((wave * 2 + tc) * 64 + lane) * 8]);
    };
    auto compute = [&](short8 (&af)[2], int par, int ki, int kj) {
        #pragma unroll
        for (int ts = 0; ts < 6; ++ts) {
            int lw = ts * 16 + sl + kj;
            int sx = g ^ ((lw >> 1) & 3);
            short8 bf = *reinterpret_cast<const short8*>(
                &fsB[par][((ki * 98 + lw) * 4 + sx) * 8]);
            acc[ts][0] = __builtin_amdgcn_mfma_f32_16x16x32_bf16(
                af[0], bf, acc[ts][0], 0, 0, 0);
            acc[ts][1] = __builtin_amdgcn_mfma_f32_16x16x32_bf16(
                af[1], bf, acc[ts][1], 0, 0, 0);
        }
    };

    // prologue: chunk 0 staged + written; af slab 0
    loadStg(0);
    #pragma unroll
    for (int tc = 0; tc < 2; ++tc)
        af0[tc] = *reinterpret_cast<const short8*>(
            &w1p[(size_t)(((wave * 2 + tc) * 64 + lane) * 8)]);
    writeStg(0);
    __syncthreads();

    for (int ccp = 0; ccp < 8; ++ccp) {
        #pragma unroll
        for (int par = 0; par < 2; ++par) {
            const int cc = ccp * 2 + par;
            if (cc < 15) loadStg(cc + 1);           // issue early
            #pragma unroll
            for (int tap = 0; tap < 9; ++tap) {
                const int sbr = cc * 9 + tap;
                const int ki = tap / 3, kj = tap % 3;
                if (((par + tap) & 1) == 0) {
                    if (sbr < 143) afload(af1, sbr + 1);
                    compute(af0, par, ki, kj);
                } else {
                    if (sbr < 143) afload(af0, sbr + 1);
                    compute(af1, par, ki, kj);
                }
            }
            if (cc < 15) {                           // write late, one barrier
                writeStg(par ^ 1);
                __syncthreads();
            }
        }
    }

    const size_t rowbase = ((size_t)n * HH + h);
    #pragma unroll
    for (int ts = 0; ts < 6; ++ts) {
        int sp = ts * 16 + sl;
        unsigned short* xp = &x[(rowbase * WW + sp) * CMID];
        #pragma unroll
        for (int tc = 0; tc < 2; ++tc) {
            int co0 = wave * 32 + tc * 16 + g * 4;
            const float4 bb = *reinterpret_cast<const float4*>(&b1[co0]);
            float v0 = acc[ts][tc][0] + bb.x;
            float v1 = acc[ts][tc][1] + bb.y;
            float v2 = acc[ts][tc][2] + bb.z;
            float v3 = acc[ts][tc][3] + bb.w;
            v0 = v0 > 0.f ? v0 : 0.f;
            v1 = v1 > 0.f ? v1 : 0.f;
            v2 = v2 > 0.f ? v2 : 0.f;
            v3 = v3 > 0.f ? v3 : 0.f;
            ushort4 st;
            st.x = f2bf(v0); st.y = f2bf(v1); st.z = f2bf(v2); st.w = f2bf(v3);
            *reinterpret_cast<ushort4*>(&xp[co0]) = st;
        }
    }
}

// conv2 v9 (reverted to r10-proven (256,3)): 1x1 256->576 + bias*0.25 +
// softmax + flow assembly. Block = 48 pixels, 4 waves = 4 pp-quarters,
// acc[9][3], af reused x3, softmax lane-local.
__global__ __launch_bounds__(256, 3) void conv2_kernel(
    const unsigned short* __restrict__ x,
    const unsigned short* __restrict__ w2p,
    const float* __restrict__ b2,
    const float* __restrict__ flow,
    float* __restrict__ out)
{
    __shared__ float lo[16 * 384];               // 24576 B
    const int tid = threadIdx.x;
    int bid = blockIdx.x;
    bid = (bid & 7) * 192 + (bid >> 3);          // XCD swizzle (1536 = 8*192)
    const int n = bid / 192;
    const int rem = bid % 192;
    const int h = rem >> 1, half = rem & 1;
    const int q = tid >> 6, lane = tid & 63;
    const int g = lane >> 4, sl = lane & 15;
    const int p0 = half * 48;

    f32x4 acc[9][3];
    #pragma unroll
    for (int k = 0; k < 9; ++k)
        #pragma unroll
        for (int u = 0; u < 3; ++u) acc[k][u] = (f32x4)0.0f;

    const unsigned short* xp = &x[(((size_t)n * HH + h) * WW + p0) * CMID];
    #pragma unroll
    for (int kc = 0; kc < 8; ++kc) {
        short8 bf[3];
        #pragma unroll
        for (int u = 0; u < 3; ++u)
            bf[u] = *reinterpret_cast<const short8*>(
                &xp[(u * 16 + sl) * CMID + kc * 32 + g * 8]);
        const unsigned short* wkc = &w2p[(size_t)kc * 36 * 512];
        #pragma unroll
        for (int k = 0; k < 9; ++k) {
            int tc = 4 * k + q;
            short8 af = *reinterpret_cast<const short8*>(&wkc[(tc * 64 + lane) * 8]);
            #pragma unroll
            for (int u = 0; u < 3; ++u)
                acc[k][u] = __builtin_amdgcn_mfma_f32_16x16x32_bf16(
                    af, bf[u], acc[k][u], 0, 0, 0);
        }
    }

    #pragma unroll
    for (int k = 0; k < 9; ++k) {
        int co0 = (4 * k + q) * 16 + g * 4;
        const float4 bb = *reinterpret_cast<const float4*>(&b2[co0]);
        #pragma unroll
        for (int u = 0; u < 3; ++u) {
            acc[k][u][0] = 0.25f * (acc[k][u][0] + bb.x);
            acc[k][u][1] = 0.25f * (acc[k][u][1] + bb.y);
            acc[k][u][2] = 0.25f * (acc[k][u][2] + bb.z);
            acc[k][u][3] = 0.25f * (acc[k][u][3] + bb.w);
        }
    }

    #pragma unroll
    for (int u = 0; u < 3; ++u) {
        const int s_abs = p0 + u * 16 + sl;
        float pf[2][9];
        #pragma unroll
        for (int ch = 0; ch < 2; ++ch) {
            #pragma unroll
            for (int ki = 0; ki < 3; ++ki) {
                #pragma unroll
                for (int kj = 0; kj < 3; ++kj) {
                    int hh2 = h + ki - 1, ww2 = s_abs + kj - 1;
                    float v = 0.f;
                    if ((unsigned)hh2 < HH && (unsigned)ww2 < WW)
                        v = flow[(((size_t)n * 2 + ch) * HH + hh2) * WW + ww2];
                    pf[ch][ki * 3 + kj] = 8.f * v;
                }
            }
        }
        #pragma unroll
        for (int i = 0; i < 4; ++i) {
            int pp = 16 * q + 4 * g + i;
            float L[9];
            #pragma unroll
            for (int k = 0; k < 9; ++k) L[k] = acc[k][u][i];
            float mx = L[0];
            #pragma unroll
            for (int k = 1; k < 9; ++k) mx = fmaxf(mx, L[k]);
            float e[9], sum = 0.f;
            #pragma unroll
            for (int k = 0; k < 9; ++k) { e[k] = __expf(L[k] - mx); sum += e[k]; }
            float inv = 1.f / sum;
            int py = pp >> 3, px = pp & 7;
            #pragma unroll
            for (int ch = 0; ch < 2; ++ch) {
                float o = 0.f;
                #pragma unroll
                for (int k = 0; k < 9; ++k) o += e[k] * pf[ch][k];
                lo[(ch * 8 + py) * 384 + (u * 16 + sl) * 8 + px] = o * inv;
            }
        }
    }
    __syncthreads();

    #pragma unroll
    for (int it = 0; it < 6; ++it) {
        int idx = tid + it * 256;                 // float4 index, 0..1535
        int row = idx / 96, c4 = idx - row * 96;
        int ch = row >> 3, py = row & 7;
        float4 v = *reinterpret_cast<const float4*>(&lo[row * 384 + c4 * 4]);
        *reinterpret_cast<float4*>(
            &out[(((size_t)n * 2 + ch) * 768 + h * 8 + py) * 768 +
                 half * 384 + c4 * 4]) = v;
    }
}

extern "C" void kernel_launch(void* const* d_in, const int* in_sizes, int n_in,
                              void* d_out, int out_size, void* d_ws, size_t ws_size,
                              hipStream_t stream)
{
    const float* feature = (const float*)d_in[0];
    const float* flow    = (const float*)d_in[1];
    const float* w1      = (const float*)d_in[2];
    const float* b1      = (const float*)d_in[3];
    const float* w2      = (const float*)d_in[4];
    const float* b2      = (const float*)d_in[5];
    float* out = (float*)d_out;

    const size_t x_bytes   = (size_t)NN * HH * WW * CMID * 2;
    const size_t w1p_bytes = (size_t)144 * 8192 * 2;
    const size_t w2p_bytes = (size_t)CO2 * CMID * 2;
    if (ws_size < x_bytes + w1p_bytes + w2p_bytes) return;

    char* ws = (char*)d_ws;
    unsigned short* xbuf = (unsigned short*)ws;
    unsigned short* w1p  = (unsigned short*)(ws + x_bytes);
    unsigned short* w2p  = (unsigned short*)(ws + x_bytes + w1p_bytes);

    prep_w_kernel<<<4608, 256, 0, stream>>>(w1, w2, w1p, w2p);
    conv1_kernel<<<NN * HH, 512, 0, stream>>>(feature, w1p, b1, xbuf);
    conv2_kernel<<<NN * HH * 2, 256, 0, stream>>>(xbuf, w2p, b2, flow, out);
}